// Round 1
// baseline (2816.468 us; speedup 1.0000x reference)
//
#include <hip/hip_runtime.h>
#include <math.h>

// ============================================================================
// CliffordFourierHead — Cl(3,0) CGENN block on MI355X. Round 0: correct fp32.
//
// Structure:
//   All matmul-shaped work goes through gemm_kernel (per-blade 64x64-tiled
//   GEMM, multi-pass: pass0 = mv_linear term, passes 1..cnt = geometric-
//   product terms reading pair-product features P[b,n,c] (c in [0,44))).
//   Elementwise kernels: normalization, pair-product build, bias+MVSiLU,
//   channel-wise GP + MVSiLU, final bias+scale.
//
// Blade order: [1, e1, e2, e3, e12, e13, e23, e123]; grades [0,1,1,1,2,2,2,3].
// The 64-entry (i,k)->(c,t,j,sign) table below was hand-derived from the
// Cayley sign rule s = sum_t popcount((mi>>t)&mk) and verified per blade pair.
// ============================================================================

#define RSQRT2F 0.70710678118654752440f

// ---- Clifford product tables ----
// entry e: blade i (left), blade k (right), P-feature index c, triple index t,
// output blade j, sign s.
__device__ constexpr int PP_I[64] = {
  0,0,0,0,0,0,0,0,  1,1,1,1,1,1,1,1,  2,2,2,2,2,2,2,2,  3,3,3,3,3,3,3,3,
  4,4,4,4,4,4,4,4,  5,5,5,5,5,5,5,5,  6,6,6,6,6,6,6,6,  7,7,7,7,7,7,7,7};
__device__ constexpr int PP_K[64] = {
  0,1,2,3,4,5,6,7,  0,1,2,3,4,5,6,7,  0,1,2,3,4,5,6,7,  0,1,2,3,4,5,6,7,
  0,1,2,3,4,5,6,7,  0,1,2,3,4,5,6,7,  0,1,2,3,4,5,6,7,  0,1,2,3,4,5,6,7};
__device__ constexpr int PP_C[64] = {
   0, 1, 2, 3, 4, 5, 6, 7,
   9, 8,15,16,13,14,21,20,
  10,15, 8,17,12,21,14,19,
  11,16,17, 8,21,12,13,18,
  29,24,23,35,22,34,33,28,
  30,25,35,23,34,22,32,27,
  31,35,25,24,33,32,22,26,
  43,42,41,40,39,38,37,36};
__device__ constexpr int PP_T[64] = {
   0, 1, 1, 1, 2, 2, 2, 3,
   5, 4, 7, 7, 6, 6, 9, 8,
   5, 7, 4, 7, 6, 9, 6, 8,
   5, 7, 7, 4, 9, 6, 6, 8,
  13,11,11,15,10,14,14,12,
  13,11,15,11,14,10,14,12,
  13,15,11,11,14,14,10,12,
  19,18,18,18,17,17,17,16};
__device__ constexpr int PP_J[64] = {
  0,1,2,3,4,5,6,7,
  1,0,4,5,2,3,7,6,
  2,4,0,6,1,7,3,5,
  3,5,6,0,7,1,2,4,
  4,2,1,7,0,6,5,3,
  5,3,7,1,6,0,4,2,
  6,7,3,2,5,4,0,1,
  7,6,5,4,3,2,1,0};
__device__ constexpr float PP_S[64] = {
  1, 1, 1, 1, 1, 1, 1, 1,
  1, 1, 1, 1, 1, 1, 1, 1,
  1,-1, 1, 1,-1,-1, 1,-1,
  1,-1,-1, 1, 1,-1,-1, 1,
  1,-1, 1, 1,-1,-1, 1,-1,
  1,-1,-1, 1, 1,-1,-1, 1,
  1, 1,-1, 1,-1, 1,-1,-1,
  1, 1,-1, 1,-1, 1,-1,-1};

// per-output-blade GP pass lists: which P column (c) with which weight path (t)
__device__ constexpr int GJ_CNT[8] = {4,6,6,6,6,6,6,4};
__device__ constexpr int GJ_C[8][6] = {
  {0,8,22,36,0,0},
  {1,9,12,23,26,37},
  {2,10,13,24,27,38},
  {3,11,14,25,28,39},
  {4,15,18,29,32,40},
  {5,16,19,30,33,41},
  {6,17,20,31,34,42},
  {7,21,35,43,0,0}};
__device__ constexpr int GJ_T[8][6] = {
  {0,4,10,16,0,0},
  {1,5,6,11,12,17},
  {1,5,6,11,12,17},
  {1,5,6,11,12,17},
  {2,7,8,13,14,18},
  {2,7,8,13,14,18},
  {2,7,8,13,14,18},
  {3,9,15,19,0,0}};
__device__ constexpr int GRADE[8] = {0,1,1,1,2,2,2,3};

__device__ inline float sigm(float x) { return 1.0f / (1.0f + expf(-x)); }

// ============================================================================
// Unified per-blade GEMM.
//   out[b, m, j] = sum_n actA[(b*N+n)*8 + j] * wL[(m*N+n)*4 + grade(j)]
//     (+ if aug) sum_p sum_n actP[(b*N+n)*44 + GJ_C[j][p]] * wG[(m*N+n)*20 + GJ_T[j][p]]
// Tile 64(b) x 64(m), 256 threads, 4x4 micro, K-chunk 16.
// ============================================================================
#define TB 64
#define TM 64
#define TK 16

__global__ __launch_bounds__(256) void gemm_kernel(
    const float* __restrict__ actA, const float* __restrict__ actP,
    const float* __restrict__ wL,   const float* __restrict__ wG,
    float* __restrict__ out, int N, int M, int aug)
{
  const int j  = blockIdx.z;
  const int b0 = blockIdx.y * TB;
  const int m0 = blockIdx.x * TM;
  const int tx = threadIdx.x & 15;   // m micro-tile
  const int ty = threadIdx.x >> 4;   // b micro-tile

  __shared__ float As[TK][TB + 1];
  __shared__ float Bs[TK][TM + 1];

  float acc[4][4] = {{0.f}};
  const int g = GRADE[j];
  const int npass = aug ? (1 + GJ_CNT[j]) : 1;

  for (int p = 0; p < npass; ++p) {
    const float* abase; int aoff, astr;
    const float* wbase; int woff, wstr;
    if (p == 0) { abase = actA; aoff = j;              astr = 8;  wbase = wL; woff = g;              wstr = 4;  }
    else        { abase = actP; aoff = GJ_C[j][p - 1]; astr = 44; wbase = wG; woff = GJ_T[j][p - 1]; wstr = 20; }

    for (int k0 = 0; k0 < N; k0 += TK) {
      __syncthreads();
      #pragma unroll
      for (int q = 0; q < 4; ++q) {
        int e  = threadIdx.x + q * 256;
        int kk = e & 15;       // k fast -> smaller global stride across lanes
        int rr = e >> 4;       // row (b or m)
        As[kk][rr] = abase[aoff + ((b0 + rr) * N + (k0 + kk)) * astr];
        Bs[kk][rr] = wbase[woff + ((m0 + rr) * N + (k0 + kk)) * wstr];
      }
      __syncthreads();
      #pragma unroll
      for (int kk = 0; kk < TK; ++kk) {
        float av[4], bv[4];
        #pragma unroll
        for (int u = 0; u < 4; ++u) av[u] = As[kk][ty * 4 + u];
        #pragma unroll
        for (int u = 0; u < 4; ++u) bv[u] = Bs[kk][tx * 4 + u];
        #pragma unroll
        for (int ib = 0; ib < 4; ++ib)
          #pragma unroll
          for (int im = 0; im < 4; ++im)
            acc[ib][im] += av[ib] * bv[im];
      }
    }
  }

  #pragma unroll
  for (int ib = 0; ib < 4; ++ib)
    #pragma unroll
    for (int im = 0; im < 4; ++im)
      out[((b0 + ty * 4 + ib) * M + (m0 + tx * 4 + im)) * 8 + j] = acc[ib][im];
}

// ============================================================================
// Elementwise kernels (one thread per (batch, channel) multivector)
// ============================================================================

// CGENN NormalizationLayer, in place: x /= (sigmoid(a)*(|x|_g - 1) + 1 + eps)
__global__ void norm_kernel(float* __restrict__ io, const float* __restrict__ a,
                            int total, int M)
{
  int t = blockIdx.x * 256 + threadIdx.x;
  if (t >= total) return;
  int m = t % M;
  float4 lo = *(const float4*)(io + (size_t)t * 8);
  float4 hi = *(const float4*)(io + (size_t)t * 8 + 4);
  float q[4];
  q[0] = sqrtf(lo.x * lo.x);
  q[1] = sqrtf(lo.y * lo.y + lo.z * lo.z + lo.w * lo.w);
  q[2] = sqrtf(hi.x * hi.x + hi.y * hi.y + hi.z * hi.z);
  q[3] = sqrtf(hi.w * hi.w);
  float s[4];
  #pragma unroll
  for (int gg = 0; gg < 4; ++gg) {
    float sa = sigm(a[m * 4 + gg]);
    s[gg] = 1.0f / (sa * (q[gg] - 1.0f) + 1.0f + 1e-6f);
  }
  lo.x *= s[0]; lo.y *= s[1]; lo.z *= s[1]; lo.w *= s[1];
  hi.x *= s[2]; hi.y *= s[2]; hi.z *= s[2]; hi.w *= s[3];
  *(float4*)(io + (size_t)t * 8)     = lo;
  *(float4*)(io + (size_t)t * 8 + 4) = hi;
}

// pair-product features: P[t,c] = sum over Cayley entries sign * u[i] * v[k]
__global__ void pair_kernel(const float* __restrict__ u8, const float* __restrict__ v8,
                            float* __restrict__ P, int total)
{
  int t = blockIdx.x * 256 + threadIdx.x;
  if (t >= total) return;
  float u[8], v[8];
  *(float4*)(u)     = *(const float4*)(u8 + (size_t)t * 8);
  *(float4*)(u + 4) = *(const float4*)(u8 + (size_t)t * 8 + 4);
  *(float4*)(v)     = *(const float4*)(v8 + (size_t)t * 8);
  *(float4*)(v + 4) = *(const float4*)(v8 + (size_t)t * 8 + 4);
  float p[44];
  #pragma unroll
  for (int c = 0; c < 44; ++c) p[c] = 0.f;
  #pragma unroll
  for (int e = 0; e < 64; ++e)
    p[PP_C[e]] += PP_S[e] * u[PP_I[e]] * v[PP_K[e]];
  float* dst = P + (size_t)t * 44;
  #pragma unroll
  for (int q = 0; q < 11; ++q)
    *(float4*)(dst + q * 4) = make_float4(p[q*4], p[q*4+1], p[q*4+2], p[q*4+3]);
}

// h = mv_silu((pre + bias_on_blade0) / sqrt2), in place
__global__ void bias_silu_kernel(float* __restrict__ io, const float* __restrict__ bias,
                                 const float* __restrict__ ga, const float* __restrict__ gb,
                                 int total, int M)
{
  int t = blockIdx.x * 256 + threadIdx.x;
  if (t >= total) return;
  int m = t % M;
  float v[8];
  *(float4*)(v)     = *(const float4*)(io + (size_t)t * 8);
  *(float4*)(v + 4) = *(const float4*)(io + (size_t)t * 8 + 4);
  v[0] += bias[m];
  #pragma unroll
  for (int jj = 0; jj < 8; ++jj) v[jj] *= RSQRT2F;
  float inv[4];
  inv[0] = v[0];
  inv[1] = v[1]*v[1] + v[2]*v[2] + v[3]*v[3];
  inv[2] = v[4]*v[4] + v[5]*v[5] + v[6]*v[6];
  inv[3] = v[7]*v[7];
  float gt[4];
  #pragma unroll
  for (int gg = 0; gg < 4; ++gg)
    gt[gg] = sigm(ga[m * 4 + gg] * inv[gg] + gb[m * 4 + gg]);
  #pragma unroll
  for (int jj = 0; jj < 8; ++jj) v[jj] *= gt[GRADE[jj]];
  *(float4*)(io + (size_t)t * 8)     = *(float4*)(v);
  *(float4*)(io + (size_t)t * 8 + 4) = *(float4*)(v + 4);
}

// h2 = mv_silu((llg_pre + bias0 + channelwise GP(h, hr; wg)) / sqrt2), in place on llg_pre
__global__ void cw_silu_kernel(float* __restrict__ io, const float* __restrict__ h,
                               const float* __restrict__ hr, const float* __restrict__ wg,
                               const float* __restrict__ bias,
                               const float* __restrict__ ga, const float* __restrict__ gb,
                               int total, int M)
{
  int t = blockIdx.x * 256 + threadIdx.x;
  if (t >= total) return;
  int n = t % M;
  float acc[8], u[8], v[8], w[20];
  *(float4*)(acc)     = *(const float4*)(io + (size_t)t * 8);
  *(float4*)(acc + 4) = *(const float4*)(io + (size_t)t * 8 + 4);
  *(float4*)(u)     = *(const float4*)(h + (size_t)t * 8);
  *(float4*)(u + 4) = *(const float4*)(h + (size_t)t * 8 + 4);
  *(float4*)(v)     = *(const float4*)(hr + (size_t)t * 8);
  *(float4*)(v + 4) = *(const float4*)(hr + (size_t)t * 8 + 4);
  #pragma unroll
  for (int q = 0; q < 5; ++q)
    *(float4*)(w + q * 4) = *(const float4*)(wg + (size_t)n * 20 + q * 4);
  acc[0] += bias[n];
  #pragma unroll
  for (int e = 0; e < 64; ++e)
    acc[PP_J[e]] += PP_S[e] * u[PP_I[e]] * v[PP_K[e]] * w[PP_T[e]];
  #pragma unroll
  for (int jj = 0; jj < 8; ++jj) acc[jj] *= RSQRT2F;
  float inv[4];
  inv[0] = acc[0];
  inv[1] = acc[1]*acc[1] + acc[2]*acc[2] + acc[3]*acc[3];
  inv[2] = acc[4]*acc[4] + acc[5]*acc[5] + acc[6]*acc[6];
  inv[3] = acc[7]*acc[7];
  float gt[4];
  #pragma unroll
  for (int gg = 0; gg < 4; ++gg)
    gt[gg] = sigm(ga[n * 4 + gg] * inv[gg] + gb[n * 4 + gg]);
  #pragma unroll
  for (int jj = 0; jj < 8; ++jj) acc[jj] *= gt[GRADE[jj]];
  *(float4*)(io + (size_t)t * 8)     = *(float4*)(acc);
  *(float4*)(io + (size_t)t * 8 + 4) = *(float4*)(acc + 4);
}

// out = (pre + bias_on_blade0) / sqrt2
__global__ void final_kernel(const float* __restrict__ pre, const float* __restrict__ bias,
                             float* __restrict__ out, int total, int M)
{
  int t = blockIdx.x * 256 + threadIdx.x;
  if (t >= total) return;
  int m = t % M;
  float v[8];
  *(float4*)(v)     = *(const float4*)(pre + (size_t)t * 8);
  *(float4*)(v + 4) = *(const float4*)(pre + (size_t)t * 8 + 4);
  v[0] += bias[m];
  #pragma unroll
  for (int jj = 0; jj < 8; ++jj) v[jj] *= RSQRT2F;
  *(float4*)(out + (size_t)t * 8)     = *(float4*)(v);
  *(float4*)(out + (size_t)t * 8 + 4) = *(float4*)(v + 4);
}

// ============================================================================
extern "C" void kernel_launch(void* const* d_in, const int* in_sizes, int n_in,
                              void* d_out, int out_size, void* d_ws, size_t ws_size,
                              hipStream_t stream)
{
  const float* x     = (const float*)d_in[0];
  const float* lr1_w = (const float*)d_in[1];
  const float* n1_a  = (const float*)d_in[2];
  const float* ll1_w = (const float*)d_in[3];
  const float* ll1_b = (const float*)d_in[4];
  const float* w1    = (const float*)d_in[5];
  const float* act_a = (const float*)d_in[6];
  const float* act_b = (const float*)d_in[7];
  const float* lrg_w = (const float*)d_in[8];
  const float* ng_a  = (const float*)d_in[9];
  const float* llg_w = (const float*)d_in[10];
  const float* llg_b = (const float*)d_in[11];
  const float* wg    = (const float*)d_in[12];
  const float* lr2_w = (const float*)d_in[13];
  const float* n2_a  = (const float*)d_in[14];
  const float* ll2_w = (const float*)d_in[15];
  const float* ll2_b = (const float*)d_in[16];
  const float* w2    = (const float*)d_in[17];
  float* out = (float*)d_out;

  // workspace layout (floats): P(1024*512*44) | ws0(1024*256*8) | ws1,ws2,ws3(1024*512*8)
  float* P   = (float*)d_ws;
  float* ws0 = P   + (size_t)1024 * 512 * 44;
  float* ws1 = ws0 + (size_t)1024 * 256 * 8;
  float* ws2 = ws1 + (size_t)1024 * 512 * 8;
  float* ws3 = ws2 + (size_t)1024 * 512 * 8;

  dim3 blk(256);
  const int ew256 = (1024 * 256) / 256;  // elementwise blocks, 256-channel layers
  const int ew512 = (1024 * 512) / 256;

  // fcgp1: xr = norm(mv_linear(x, lr1_w)); h1 = silu((lin + bias + GP)/sqrt2)
  gemm_kernel<<<dim3(4, 16, 8), blk, 0, stream>>>(x, nullptr, lr1_w, nullptr, ws0, 256, 256, 0);
  norm_kernel<<<ew256, blk, 0, stream>>>(ws0, n1_a, 1024 * 256, 256);
  pair_kernel<<<ew256, blk, 0, stream>>>(x, ws0, P, 1024 * 256);
  gemm_kernel<<<dim3(8, 16, 8), blk, 0, stream>>>(x, P, ll1_w, w1, ws1, 256, 512, 1);
  bias_silu_kernel<<<ew512, blk, 0, stream>>>(ws1, ll1_b, act_a, act_b, 1024 * 512, 512);

  // channel-wise GP layer
  gemm_kernel<<<dim3(8, 16, 8), blk, 0, stream>>>(ws1, nullptr, lrg_w, nullptr, ws2, 512, 512, 0);
  norm_kernel<<<ew512, blk, 0, stream>>>(ws2, ng_a, 1024 * 512, 512);
  gemm_kernel<<<dim3(8, 16, 8), blk, 0, stream>>>(ws1, nullptr, llg_w, nullptr, ws3, 512, 512, 0);
  cw_silu_kernel<<<ew512, blk, 0, stream>>>(ws3, ws1, ws2, wg, llg_b, act_a, act_b, 1024 * 512, 512);

  // fcgp2
  gemm_kernel<<<dim3(8, 16, 8), blk, 0, stream>>>(ws3, nullptr, lr2_w, nullptr, ws2, 512, 512, 0);
  norm_kernel<<<ew512, blk, 0, stream>>>(ws2, n2_a, 1024 * 512, 512);
  pair_kernel<<<ew512, blk, 0, stream>>>(ws3, ws2, P, 1024 * 512);
  gemm_kernel<<<dim3(2, 16, 8), blk, 0, stream>>>(ws3, P, ll2_w, w2, ws1, 512, 128, 1);
  final_kernel<<<(1024 * 128) / 256, blk, 0, stream>>>(ws1, ll2_b, out, 1024 * 128, 128);
}

// Round 2
// 353.604 us; speedup vs baseline: 7.9650x; 7.9650x over previous
//
#include <hip/hip_runtime.h>
#include <math.h>

// ============================================================================
// CliffordFourierHead — Cl(3,0) CGENN block. Round 2: planar layouts + bf16
// MFMA GEMMs (16x16x32, 128x128 tile), fp32 masters between layers.
//
// Layouts:
//   activations: planar fp32 [8][B*M] planes + bf16 shadow planes for GEMM A
//   pair-product features: bf16 planes [44][B*N]
//   weights: repacked per call to bf16 planes [S][M][N] (k contiguous)
// GEMM: out_j[b,m] = sum_k A_j[b,k] W_g[m,k]  (+ GP passes P_c · W_t)
// ============================================================================

typedef unsigned short u16;
typedef __attribute__((ext_vector_type(8))) short short8;
typedef __attribute__((ext_vector_type(4))) float f32x4;

#define RSQRT2F 0.70710678118654752440f

// ---- Clifford product tables (verified in round 0/1) ----
__device__ constexpr int PP_I[64] = {
  0,0,0,0,0,0,0,0,  1,1,1,1,1,1,1,1,  2,2,2,2,2,2,2,2,  3,3,3,3,3,3,3,3,
  4,4,4,4,4,4,4,4,  5,5,5,5,5,5,5,5,  6,6,6,6,6,6,6,6,  7,7,7,7,7,7,7,7};
__device__ constexpr int PP_K[64] = {
  0,1,2,3,4,5,6,7,  0,1,2,3,4,5,6,7,  0,1,2,3,4,5,6,7,  0,1,2,3,4,5,6,7,
  0,1,2,3,4,5,6,7,  0,1,2,3,4,5,6,7,  0,1,2,3,4,5,6,7,  0,1,2,3,4,5,6,7};
__device__ constexpr int PP_C[64] = {
   0, 1, 2, 3, 4, 5, 6, 7,
   9, 8,15,16,13,14,21,20,
  10,15, 8,17,12,21,14,19,
  11,16,17, 8,21,12,13,18,
  29,24,23,35,22,34,33,28,
  30,25,35,23,34,22,32,27,
  31,35,25,24,33,32,22,26,
  43,42,41,40,39,38,37,36};
__device__ constexpr int PP_T[64] = {
   0, 1, 1, 1, 2, 2, 2, 3,
   5, 4, 7, 7, 6, 6, 9, 8,
   5, 7, 4, 7, 6, 9, 6, 8,
   5, 7, 7, 4, 9, 6, 6, 8,
  13,11,11,15,10,14,14,12,
  13,11,15,11,14,10,14,12,
  13,15,11,11,14,14,10,12,
  19,18,18,18,17,17,17,16};
__device__ constexpr int PP_J[64] = {
  0,1,2,3,4,5,6,7,
  1,0,4,5,2,3,7,6,
  2,4,0,6,1,7,3,5,
  3,5,6,0,7,1,2,4,
  4,2,1,7,0,6,5,3,
  5,3,7,1,6,0,4,2,
  6,7,3,2,5,4,0,1,
  7,6,5,4,3,2,1,0};
__device__ constexpr float PP_S[64] = {
  1, 1, 1, 1, 1, 1, 1, 1,
  1, 1, 1, 1, 1, 1, 1, 1,
  1,-1, 1, 1,-1,-1, 1,-1,
  1,-1,-1, 1, 1,-1,-1, 1,
  1,-1, 1, 1,-1,-1, 1,-1,
  1,-1,-1, 1, 1,-1,-1, 1,
  1, 1,-1, 1,-1, 1,-1,-1,
  1, 1,-1, 1,-1, 1,-1,-1};

__device__ constexpr int GJ_CNT[8] = {4,6,6,6,6,6,6,4};
__device__ constexpr int GJ_C[8][6] = {
  {0,8,22,36,0,0},
  {1,9,12,23,26,37},
  {2,10,13,24,27,38},
  {3,11,14,25,28,39},
  {4,15,18,29,32,40},
  {5,16,19,30,33,41},
  {6,17,20,31,34,42},
  {7,21,35,43,0,0}};
__device__ constexpr int GJ_T[8][6] = {
  {0,4,10,16,0,0},
  {1,5,6,11,12,17},
  {1,5,6,11,12,17},
  {1,5,6,11,12,17},
  {2,7,8,13,14,18},
  {2,7,8,13,14,18},
  {2,7,8,13,14,18},
  {3,9,15,19,0,0}};
__device__ constexpr int GRADE[8] = {0,1,1,1,2,2,2,3};

__device__ inline float sigm(float x) { return 1.0f / (1.0f + expf(-x)); }
__device__ inline u16 f2bf(float f) {
  unsigned u = __float_as_uint(f);
  return (u16)((u + 0x7fffu + ((u >> 16) & 1u)) >> 16);
}
__device__ inline float bf2f(u16 h) { return __uint_as_float(((unsigned)h) << 16); }

// ============================================================================
// bf16 MFMA GEMM, multi-pass (pass0 = linear, passes 1.. = GP feature planes).
// Tile 128(b) x 128(m), BK=64, 4 waves in 2x2, each wave 4x4 of 16x16x32 MFMA.
// LDS XOR-swizzled on 16B granules so frag ds_read_b128 is ~conflict-free.
// ============================================================================
#define BT 128
#define MT 128
#define BKc 64

__global__ __launch_bounds__(256) void mfma_gemm(
    const u16* __restrict__ Alin, const u16* __restrict__ Pfeat,
    const u16* __restrict__ WLin, const u16* __restrict__ WGp,
    float* __restrict__ outp, int N, int M, int aug, int planeA, int planeO)
{
  const int j    = blockIdx.z;
  const int b0   = blockIdx.y * BT;
  const int m0   = blockIdx.x * MT;
  const int tid  = threadIdx.x;
  const int lane = tid & 63;
  const int wave = tid >> 6;
  const int wr   = wave >> 1;   // b-half
  const int wc   = wave & 1;    // m-half
  const int l15  = lane & 15;
  const int lq   = lane >> 4;   // quad 0..3

  __shared__ u16 As[BT * BKc];
  __shared__ u16 Bs[MT * BKc];

  f32x4 zero = {0.f, 0.f, 0.f, 0.f};
  f32x4 acc[4][4];
  #pragma unroll
  for (int r = 0; r < 4; ++r)
    #pragma unroll
    for (int c = 0; c < 4; ++c) acc[r][c] = zero;

  const int g = GRADE[j];
  const int npass = aug ? (1 + GJ_CNT[j]) : 1;
  const int lrow = tid >> 3;   // 0..31
  const int lcg  = tid & 7;    // 16B granule 0..7

  for (int p = 0; p < npass; ++p) {
    const u16* Abase = (p == 0) ? Alin + (size_t)j * planeA
                                : Pfeat + (size_t)GJ_C[j][p - 1] * planeA;
    const u16* Wbase = (p == 0) ? WLin + (size_t)g * M * N
                                : WGp + (size_t)GJ_T[j][p - 1] * M * N;

    for (int k0 = 0; k0 < N; k0 += BKc) {
      __syncthreads();
      #pragma unroll
      for (int q = 0; q < 4; ++q) {
        int row = lrow + q * 32;
        short8 va = *(const short8*)(Abase + (size_t)(b0 + row) * N + k0 + lcg * 8);
        *(short8*)(&As[row * BKc + (lcg ^ (row & 7)) * 8]) = va;
      }
      #pragma unroll
      for (int q = 0; q < 4; ++q) {
        int row = lrow + q * 32;
        short8 vb = *(const short8*)(Wbase + (size_t)(m0 + row) * N + k0 + lcg * 8);
        *(short8*)(&Bs[row * BKc + (lcg ^ (row & 7)) * 8]) = vb;
      }
      __syncthreads();
      #pragma unroll
      for (int s = 0; s < 2; ++s) {
        const int kq = s * 4 + lq;   // k granule within chunk
        short8 af[4], bfr[4];
        #pragma unroll
        for (int r = 0; r < 4; ++r) {
          int row = wr * 64 + r * 16 + l15;
          af[r] = *(const short8*)(&As[row * BKc + (kq ^ (row & 7)) * 8]);
        }
        #pragma unroll
        for (int c = 0; c < 4; ++c) {
          int row = wc * 64 + c * 16 + l15;
          bfr[c] = *(const short8*)(&Bs[row * BKc + (kq ^ (row & 7)) * 8]);
        }
        #pragma unroll
        for (int r = 0; r < 4; ++r)
          #pragma unroll
          for (int c = 0; c < 4; ++c)
            acc[r][c] = __builtin_amdgcn_mfma_f32_16x16x32_bf16(af[r], bfr[c], acc[r][c], 0, 0, 0);
      }
    }
  }

  // epilogue: D row = (lane>>4)*4 + reg (b-index), col = lane&15 (m-index)
  #pragma unroll
  for (int r = 0; r < 4; ++r) {
    #pragma unroll
    for (int c = 0; c < 4; ++c) {
      #pragma unroll
      for (int e = 0; e < 4; ++e) {
        int bb = b0 + wr * 64 + r * 16 + lq * 4 + e;
        int mm = m0 + wc * 64 + c * 16 + l15;
        outp[(size_t)j * planeO + (size_t)bb * M + mm] = acc[r][c][e];
      }
    }
  }
}

// ============================================================================
// Repack + elementwise kernels (planar)
// ============================================================================

// weights [m,n,S] fp32 -> bf16 planes [S][M*N]
__global__ void repack_w(const float* __restrict__ in, u16* __restrict__ outp,
                         int MN, int S)
{
  int mn = blockIdx.x * 256 + threadIdx.x;
  if (mn >= MN) return;
  for (int s = 0; s < S; ++s)
    outp[(size_t)s * MN + mn] = f2bf(in[(size_t)mn * S + s]);
}

// x [B,N,8] fp32 interleaved -> bf16 planes [8][B*N]
__global__ void xcast_kernel(const float* __restrict__ x, u16* __restrict__ xp, int PS)
{
  int t = blockIdx.x * 256 + threadIdx.x;
  if (t >= PS) return;
  float v[8];
  *(float4*)(v)     = *(const float4*)(x + (size_t)t * 8);
  *(float4*)(v + 4) = *(const float4*)(x + (size_t)t * 8 + 4);
  #pragma unroll
  for (int jj = 0; jj < 8; ++jj) xp[(size_t)jj * PS + t] = f2bf(v[jj]);
}

// CGENN normalization in place on fp32 planes
__global__ void norm_p(float* __restrict__ io, const float* __restrict__ a,
                       int PS, int M)
{
  int t = blockIdx.x * 256 + threadIdx.x;
  if (t >= PS) return;
  int m = t % M;
  float v[8];
  #pragma unroll
  for (int jj = 0; jj < 8; ++jj) v[jj] = io[(size_t)jj * PS + t];
  float q[4];
  q[0] = sqrtf(v[0] * v[0]);
  q[1] = sqrtf(v[1] * v[1] + v[2] * v[2] + v[3] * v[3]);
  q[2] = sqrtf(v[4] * v[4] + v[5] * v[5] + v[6] * v[6]);
  q[3] = sqrtf(v[7] * v[7]);
  float s[4];
  #pragma unroll
  for (int gg = 0; gg < 4; ++gg) {
    float sa = sigm(a[m * 4 + gg]);
    s[gg] = 1.0f / (sa * (q[gg] - 1.0f) + 1.0f + 1e-6f);
  }
  #pragma unroll
  for (int jj = 0; jj < 8; ++jj) io[(size_t)jj * PS + t] = v[jj] * s[GRADE[jj]];
}

// pair-product features: u bf16 planes, v fp32 planes -> P bf16 planes [44][PS]
__global__ void pair_p(const u16* __restrict__ up, const float* __restrict__ vp,
                       u16* __restrict__ Pp, int PS)
{
  int t = blockIdx.x * 256 + threadIdx.x;
  if (t >= PS) return;
  float u[8], v[8];
  #pragma unroll
  for (int jj = 0; jj < 8; ++jj) {
    u[jj] = bf2f(up[(size_t)jj * PS + t]);
    v[jj] = vp[(size_t)jj * PS + t];
  }
  float p[44];
  #pragma unroll
  for (int c = 0; c < 44; ++c) p[c] = 0.f;
  #pragma unroll
  for (int e = 0; e < 64; ++e)
    p[PP_C[e]] += PP_S[e] * u[PP_I[e]] * v[PP_K[e]];
  #pragma unroll
  for (int c = 0; c < 44; ++c) Pp[(size_t)c * PS + t] = f2bf(p[c]);
}

// h = mv_silu((pre + bias0)/sqrt2), in place, + bf16 shadow planes
__global__ void bias_silu_p(float* __restrict__ io, u16* __restrict__ sh,
                            const float* __restrict__ bias,
                            const float* __restrict__ ga, const float* __restrict__ gb,
                            int PS, int M)
{
  int t = blockIdx.x * 256 + threadIdx.x;
  if (t >= PS) return;
  int m = t % M;
  float v[8];
  #pragma unroll
  for (int jj = 0; jj < 8; ++jj) v[jj] = io[(size_t)jj * PS + t];
  v[0] += bias[m];
  #pragma unroll
  for (int jj = 0; jj < 8; ++jj) v[jj] *= RSQRT2F;
  float inv[4];
  inv[0] = v[0];
  inv[1] = v[1]*v[1] + v[2]*v[2] + v[3]*v[3];
  inv[2] = v[4]*v[4] + v[5]*v[5] + v[6]*v[6];
  inv[3] = v[7]*v[7];
  float gt[4];
  #pragma unroll
  for (int gg = 0; gg < 4; ++gg)
    gt[gg] = sigm(ga[m * 4 + gg] * inv[gg] + gb[m * 4 + gg]);
  #pragma unroll
  for (int jj = 0; jj < 8; ++jj) {
    float o = v[jj] * gt[GRADE[jj]];
    io[(size_t)jj * PS + t] = o;
    sh[(size_t)jj * PS + t] = f2bf(o);
  }
}

// h2 = mv_silu((llg_pre + bias0 + cwGP(h, hr; wg))/sqrt2) -> bf16 shadow planes
__global__ void cw_silu_p(const float* __restrict__ llg, const float* __restrict__ up,
                          const float* __restrict__ vp, const float* __restrict__ wg,
                          const float* __restrict__ bias,
                          const float* __restrict__ ga, const float* __restrict__ gb,
                          u16* __restrict__ sh, int PS, int M)
{
  int t = blockIdx.x * 256 + threadIdx.x;
  if (t >= PS) return;
  int n = t % M;
  float acc[8], u[8], v[8], w[20];
  #pragma unroll
  for (int jj = 0; jj < 8; ++jj) {
    acc[jj] = llg[(size_t)jj * PS + t];
    u[jj]   = up[(size_t)jj * PS + t];
    v[jj]   = vp[(size_t)jj * PS + t];
  }
  #pragma unroll
  for (int q = 0; q < 5; ++q)
    *(float4*)(w + q * 4) = *(const float4*)(wg + (size_t)n * 20 + q * 4);
  acc[0] += bias[n];
  #pragma unroll
  for (int e = 0; e < 64; ++e)
    acc[PP_J[e]] += PP_S[e] * u[PP_I[e]] * v[PP_K[e]] * w[PP_T[e]];
  float inv[4];
  #pragma unroll
  for (int jj = 0; jj < 8; ++jj) acc[jj] *= RSQRT2F;
  inv[0] = acc[0];
  inv[1] = acc[1]*acc[1] + acc[2]*acc[2] + acc[3]*acc[3];
  inv[2] = acc[4]*acc[4] + acc[5]*acc[5] + acc[6]*acc[6];
  inv[3] = acc[7]*acc[7];
  float gt[4];
  #pragma unroll
  for (int gg = 0; gg < 4; ++gg)
    gt[gg] = sigm(ga[n * 4 + gg] * inv[gg] + gb[n * 4 + gg]);
  #pragma unroll
  for (int jj = 0; jj < 8; ++jj)
    sh[(size_t)jj * PS + t] = f2bf(acc[jj] * gt[GRADE[jj]]);
}

// out[b,m,j] = (pre_j[b*M+m] + bias0)/sqrt2, planar -> interleaved
__global__ void final_p(const float* __restrict__ pre, const float* __restrict__ bias,
                        float* __restrict__ outp, int PS, int M)
{
  int t = blockIdx.x * 256 + threadIdx.x;
  if (t >= PS) return;
  int m = t % M;
  float v[8];
  #pragma unroll
  for (int jj = 0; jj < 8; ++jj) v[jj] = pre[(size_t)jj * PS + t];
  v[0] += bias[m];
  #pragma unroll
  for (int jj = 0; jj < 8; ++jj) v[jj] *= RSQRT2F;
  *(float4*)(outp + (size_t)t * 8)     = *(float4*)(v);
  *(float4*)(outp + (size_t)t * 8 + 4) = *(float4*)(v + 4);
}

// ============================================================================
extern "C" void kernel_launch(void* const* d_in, const int* in_sizes, int n_in,
                              void* d_out, int out_size, void* d_ws, size_t ws_size,
                              hipStream_t stream)
{
  const float* x     = (const float*)d_in[0];
  const float* lr1_w = (const float*)d_in[1];
  const float* n1_a  = (const float*)d_in[2];
  const float* ll1_w = (const float*)d_in[3];
  const float* ll1_b = (const float*)d_in[4];
  const float* w1    = (const float*)d_in[5];
  const float* act_a = (const float*)d_in[6];
  const float* act_b = (const float*)d_in[7];
  const float* lrg_w = (const float*)d_in[8];
  const float* ng_a  = (const float*)d_in[9];
  const float* llg_w = (const float*)d_in[10];
  const float* llg_b = (const float*)d_in[11];
  const float* wg    = (const float*)d_in[12];
  const float* lr2_w = (const float*)d_in[13];
  const float* n2_a  = (const float*)d_in[14];
  const float* ll2_w = (const float*)d_in[15];
  const float* ll2_b = (const float*)d_in[16];
  const float* w2    = (const float*)d_in[17];
  float* out = (float*)d_out;

  // ---- workspace carve-up (bf16/u16 region, then fp32 region) ----
  u16* W = (u16*)d_ws;
  size_t o = 0;
  u16* WL1  = W + o; o +=  262144;  // [4][256*256]
  u16* WLL1 = W + o; o +=  524288;  // [4][512*256]
  u16* WG1  = W + o; o += 2621440;  // [20][512*256]
  u16* WLRG = W + o; o += 1048576;  // [4][512*512]
  u16* WLLG = W + o; o += 1048576;
  u16* WLR2 = W + o; o += 1048576;
  u16* WLL2 = W + o; o +=  262144;  // [4][128*512]
  u16* WG2  = W + o; o += 1310720;  // [20][128*512]
  u16* XB   = W + o; o += 2097152;  // [8][1024*256]
  u16* HB   = W + o; o += 4194304;  // [8][1024*512] shared h1b16/h2b16
  u16* P    = W + o; o += 23068672; // [44][1024*512]
  float* F = (float*)(W + o);       // byte offset 74,973,184 (16B aligned)
  size_t f = 0;
  float* preXr  = F + f; f += 2097152;  // [8][1024*256]
  float* h1     = F + f; f += 4194304;  // [8][1024*512]
  float* hr     = F + f; f += 4194304;  // shared hr / hr2
  float* llg    = F + f; f += 4194304;
  float* outPre = F + f; f += 1048576;  // [8][1024*128]

  dim3 blk(256);
  const int PS1 = 1024 * 256, PS2 = 1024 * 512, PSO = 1024 * 128;

  // ---- weight repacks (re-done every call; ws is re-poisoned) ----
  repack_w<<<(65536 + 255) / 256, blk, 0, stream>>>(lr1_w, WL1, 65536, 4);
  repack_w<<<(131072 + 255) / 256, blk, 0, stream>>>(ll1_w, WLL1, 131072, 4);
  repack_w<<<(131072 + 255) / 256, blk, 0, stream>>>(w1, WG1, 131072, 20);
  repack_w<<<(262144 + 255) / 256, blk, 0, stream>>>(lrg_w, WLRG, 262144, 4);
  repack_w<<<(262144 + 255) / 256, blk, 0, stream>>>(llg_w, WLLG, 262144, 4);
  repack_w<<<(262144 + 255) / 256, blk, 0, stream>>>(lr2_w, WLR2, 262144, 4);
  repack_w<<<(65536 + 255) / 256, blk, 0, stream>>>(ll2_w, WLL2, 65536, 4);
  repack_w<<<(65536 + 255) / 256, blk, 0, stream>>>(w2, WG2, 65536, 20);
  xcast_kernel<<<PS1 / 256, blk, 0, stream>>>(x, XB, PS1);

  // ---- fcgp1 (N=256, M=512) ----
  mfma_gemm<<<dim3(2, 8, 8), blk, 0, stream>>>(XB, nullptr, WL1, nullptr, preXr, 256, 256, 0, PS1, PS1);
  norm_p<<<PS1 / 256, blk, 0, stream>>>(preXr, n1_a, PS1, 256);
  pair_p<<<PS1 / 256, blk, 0, stream>>>(XB, preXr, P, PS1);
  mfma_gemm<<<dim3(4, 8, 8), blk, 0, stream>>>(XB, P, WLL1, WG1, h1, 256, 512, 1, PS1, PS2);
  bias_silu_p<<<PS2 / 256, blk, 0, stream>>>(h1, HB, ll1_b, act_a, act_b, PS2, 512);

  // ---- channel-wise GP layer (N=512, M=512) ----
  mfma_gemm<<<dim3(4, 8, 8), blk, 0, stream>>>(HB, nullptr, WLRG, nullptr, hr, 512, 512, 0, PS2, PS2);
  norm_p<<<PS2 / 256, blk, 0, stream>>>(hr, ng_a, PS2, 512);
  mfma_gemm<<<dim3(4, 8, 8), blk, 0, stream>>>(HB, nullptr, WLLG, nullptr, llg, 512, 512, 0, PS2, PS2);
  cw_silu_p<<<PS2 / 256, blk, 0, stream>>>(llg, h1, hr, wg, llg_b, act_a, act_b, HB, PS2, 512);

  // ---- fcgp2 (N=512, M=128) ----
  mfma_gemm<<<dim3(4, 8, 8), blk, 0, stream>>>(HB, nullptr, WLR2, nullptr, hr, 512, 512, 0, PS2, PS2);
  norm_p<<<PS2 / 256, blk, 0, stream>>>(hr, n2_a, PS2, 512);
  pair_p<<<PS2 / 256, blk, 0, stream>>>(HB, hr, P, PS2);
  mfma_gemm<<<dim3(1, 8, 8), blk, 0, stream>>>(HB, P, WLL2, WG2, outPre, 512, 128, 1, PS2, PSO);
  final_p<<<PSO / 256, blk, 0, stream>>>(outPre, ll2_b, out, PSO, 128);
}

// Round 3
// 266.343 us; speedup vs baseline: 10.5746x; 1.3276x over previous
//
#include <hip/hip_runtime.h>
#include <math.h>

// ============================================================================
// CliffordFourierHead — Cl(3,0) CGENN block. Round 3: split-K GEMMs with
// consumer-side slice reduction (no atomics), fused lrg+llg dispatch, fused
// norm-into-consumer elementwise, single repack dispatch. 11 dispatches.
// ============================================================================

typedef unsigned short u16;
typedef __attribute__((ext_vector_type(8))) short short8;
typedef __attribute__((ext_vector_type(4))) float f32x4;

#define RSQRT2F 0.70710678118654752440f

// ---- Clifford product tables (verified rounds 0-2) ----
__device__ constexpr int PP_I[64] = {
  0,0,0,0,0,0,0,0,  1,1,1,1,1,1,1,1,  2,2,2,2,2,2,2,2,  3,3,3,3,3,3,3,3,
  4,4,4,4,4,4,4,4,  5,5,5,5,5,5,5,5,  6,6,6,6,6,6,6,6,  7,7,7,7,7,7,7,7};
__device__ constexpr int PP_K[64] = {
  0,1,2,3,4,5,6,7,  0,1,2,3,4,5,6,7,  0,1,2,3,4,5,6,7,  0,1,2,3,4,5,6,7,
  0,1,2,3,4,5,6,7,  0,1,2,3,4,5,6,7,  0,1,2,3,4,5,6,7,  0,1,2,3,4,5,6,7};
__device__ constexpr int PP_C[64] = {
   0, 1, 2, 3, 4, 5, 6, 7,
   9, 8,15,16,13,14,21,20,
  10,15, 8,17,12,21,14,19,
  11,16,17, 8,21,12,13,18,
  29,24,23,35,22,34,33,28,
  30,25,35,23,34,22,32,27,
  31,35,25,24,33,32,22,26,
  43,42,41,40,39,38,37,36};
__device__ constexpr int PP_T[64] = {
   0, 1, 1, 1, 2, 2, 2, 3,
   5, 4, 7, 7, 6, 6, 9, 8,
   5, 7, 4, 7, 6, 9, 6, 8,
   5, 7, 7, 4, 9, 6, 6, 8,
  13,11,11,15,10,14,14,12,
  13,11,15,11,14,10,14,12,
  13,15,11,11,14,14,10,12,
  19,18,18,18,17,17,17,16};
__device__ constexpr int PP_J[64] = {
  0,1,2,3,4,5,6,7,
  1,0,4,5,2,3,7,6,
  2,4,0,6,1,7,3,5,
  3,5,6,0,7,1,2,4,
  4,2,1,7,0,6,5,3,
  5,3,7,1,6,0,4,2,
  6,7,3,2,5,4,0,1,
  7,6,5,4,3,2,1,0};
__device__ constexpr float PP_S[64] = {
  1, 1, 1, 1, 1, 1, 1, 1,
  1, 1, 1, 1, 1, 1, 1, 1,
  1,-1, 1, 1,-1,-1, 1,-1,
  1,-1,-1, 1, 1,-1,-1, 1,
  1,-1, 1, 1,-1,-1, 1,-1,
  1,-1,-1, 1, 1,-1,-1, 1,
  1, 1,-1, 1,-1, 1,-1,-1,
  1, 1,-1, 1,-1, 1,-1,-1};

__device__ constexpr int GJ_CNT[8] = {4,6,6,6,6,6,6,4};
__device__ constexpr int GJ_C[8][6] = {
  {0,8,22,36,0,0},
  {1,9,12,23,26,37},
  {2,10,13,24,27,38},
  {3,11,14,25,28,39},
  {4,15,18,29,32,40},
  {5,16,19,30,33,41},
  {6,17,20,31,34,42},
  {7,21,35,43,0,0}};
__device__ constexpr int GJ_T[8][6] = {
  {0,4,10,16,0,0},
  {1,5,6,11,12,17},
  {1,5,6,11,12,17},
  {1,5,6,11,12,17},
  {2,7,8,13,14,18},
  {2,7,8,13,14,18},
  {2,7,8,13,14,18},
  {3,9,15,19,0,0}};
__device__ constexpr int GRADE[8] = {0,1,1,1,2,2,2,3};

__device__ inline float sigm(float x) { return 1.0f / (1.0f + expf(-x)); }
__device__ inline u16 f2bf(float f) {
  unsigned u = __float_as_uint(f);
  return (u16)((u + 0x7fffu + ((u >> 16) & 1u)) >> 16);
}
__device__ inline float bf2f(u16 h) { return __uint_as_float(((unsigned)h) << 16); }

// ============================================================================
// bf16 MFMA GEMM, multi-pass + split-K over flattened (pass, k-chunk) list.
// blockIdx.z encodes (set, j, slice): set selects {WLin,out1} vs {WLin2,out2}
// (for fusing two independent GEMMs); slice writes its own partial planes
// [slice*8+j][planeO]; consumers sum slices. Tile 128x128, BK=64, 4 waves,
// 4x4 frags of 16x16x32 bf16 MFMA, XOR-swizzled LDS.
// ============================================================================
#define BT 128
#define MT 128
#define BKc 64

__global__ __launch_bounds__(256) void mfma_gemm(
    const u16* __restrict__ Alin, const u16* __restrict__ Pfeat,
    const u16* __restrict__ WLin, const u16* __restrict__ WLin2,
    const u16* __restrict__ WGp,
    float* __restrict__ out1, float* __restrict__ out2,
    int N, int M, int aug, int planeA, int planeO, int KSbits, int KCbits)
{
  const int zz    = blockIdx.z;
  const int set   = zz >> (3 + KSbits);
  const int rem   = zz & ((8 << KSbits) - 1);
  const int j     = rem >> KSbits;
  const int slice = rem & ((1 << KSbits) - 1);
  const u16* WL   = set ? WLin2 : WLin;
  float* outp     = set ? out2 : out1;

  const int b0   = blockIdx.y * BT;
  const int m0   = blockIdx.x * MT;
  const int tid  = threadIdx.x;
  const int lane = tid & 63;
  const int wave = tid >> 6;
  const int wr   = wave >> 1;
  const int wc   = wave & 1;
  const int l15  = lane & 15;
  const int lq   = lane >> 4;

  __shared__ u16 As[BT * BKc];
  __shared__ u16 Bs[MT * BKc];

  f32x4 zero = {0.f, 0.f, 0.f, 0.f};
  f32x4 acc[4][4];
  #pragma unroll
  for (int r = 0; r < 4; ++r)
    #pragma unroll
    for (int c = 0; c < 4; ++c) acc[r][c] = zero;

  const int g = GRADE[j];
  const int npass = aug ? (1 + GJ_CNT[j]) : 1;
  const int KC = 1 << KCbits;
  const int cper = (npass << KCbits) >> KSbits;   // even division by design
  const int cbeg = slice * cper;
  const int lrow = tid >> 3;
  const int lcg  = tid & 7;

  for (int ci = cbeg; ci < cbeg + cper; ++ci) {
    const int p  = ci >> KCbits;
    const int k0 = (ci & (KC - 1)) << 6;
    const u16* Abase = (p == 0) ? Alin + (size_t)j * planeA
                                : Pfeat + (size_t)GJ_C[j][p - 1] * planeA;
    const u16* Wbase = (p == 0) ? WL + (size_t)g * M * N
                                : WGp + (size_t)GJ_T[j][p - 1] * M * N;
    __syncthreads();
    #pragma unroll
    for (int q = 0; q < 4; ++q) {
      int row = lrow + q * 32;
      short8 va = *(const short8*)(Abase + (size_t)(b0 + row) * N + k0 + lcg * 8);
      *(short8*)(&As[row * BKc + (lcg ^ (row & 7)) * 8]) = va;
    }
    #pragma unroll
    for (int q = 0; q < 4; ++q) {
      int row = lrow + q * 32;
      short8 vb = *(const short8*)(Wbase + (size_t)(m0 + row) * N + k0 + lcg * 8);
      *(short8*)(&Bs[row * BKc + (lcg ^ (row & 7)) * 8]) = vb;
    }
    __syncthreads();
    #pragma unroll
    for (int s = 0; s < 2; ++s) {
      const int kq = s * 4 + lq;
      short8 af[4], bfr[4];
      #pragma unroll
      for (int r = 0; r < 4; ++r) {
        int row = wr * 64 + r * 16 + l15;
        af[r] = *(const short8*)(&As[row * BKc + (kq ^ (row & 7)) * 8]);
      }
      #pragma unroll
      for (int c = 0; c < 4; ++c) {
        int row = wc * 64 + c * 16 + l15;
        bfr[c] = *(const short8*)(&Bs[row * BKc + (kq ^ (row & 7)) * 8]);
      }
      #pragma unroll
      for (int r = 0; r < 4; ++r)
        #pragma unroll
        for (int c = 0; c < 4; ++c)
          acc[r][c] = __builtin_amdgcn_mfma_f32_16x16x32_bf16(af[r], bfr[c], acc[r][c], 0, 0, 0);
    }
  }

  float* obase = outp + (size_t)(slice * 8 + j) * planeO;
  #pragma unroll
  for (int r = 0; r < 4; ++r)
    #pragma unroll
    for (int c = 0; c < 4; ++c)
      #pragma unroll
      for (int e = 0; e < 4; ++e) {
        int bb = b0 + wr * 64 + r * 16 + lq * 4 + e;
        int mm = m0 + wc * 64 + c * 16 + l15;
        obase[(size_t)bb * M + mm] = acc[r][c][e];
      }
}

// ============================================================================
// Fused repack: all 8 weight tensors [mn,S] fp32 -> bf16 planes [S][MN]
// ============================================================================
struct RepackDesc { const float* in; u16* out; int MN; int S; };
struct RepackArgs { RepackDesc d[8]; };

__global__ void repack_all(RepackArgs a)
{
  RepackDesc d = a.d[blockIdx.y];
  int mn = blockIdx.x * 256 + threadIdx.x;
  if (mn >= d.MN) return;
  if (d.S == 4) {
    float4 v = ((const float4*)d.in)[mn];
    d.out[(size_t)0 * d.MN + mn] = f2bf(v.x);
    d.out[(size_t)1 * d.MN + mn] = f2bf(v.y);
    d.out[(size_t)2 * d.MN + mn] = f2bf(v.z);
    d.out[(size_t)3 * d.MN + mn] = f2bf(v.w);
  } else {  // S == 20
    #pragma unroll
    for (int q = 0; q < 5; ++q) {
      float4 v = *(const float4*)(d.in + (size_t)mn * 20 + q * 4);
      d.out[(size_t)(q * 4 + 0) * d.MN + mn] = f2bf(v.x);
      d.out[(size_t)(q * 4 + 1) * d.MN + mn] = f2bf(v.y);
      d.out[(size_t)(q * 4 + 2) * d.MN + mn] = f2bf(v.z);
      d.out[(size_t)(q * 4 + 3) * d.MN + mn] = f2bf(v.w);
    }
  }
}

// x [B,N,8] fp32 interleaved -> bf16 planes [8][B*N]
__global__ void xcast_kernel(const float* __restrict__ x, u16* __restrict__ xp, int PS)
{
  int t = blockIdx.x * 256 + threadIdx.x;
  if (t >= PS) return;
  float v[8];
  *(float4*)(v)     = *(const float4*)(x + (size_t)t * 8);
  *(float4*)(v + 4) = *(const float4*)(x + (size_t)t * 8 + 4);
  #pragma unroll
  for (int jj = 0; jj < 8; ++jj) xp[(size_t)jj * PS + t] = f2bf(v[jj]);
}

// fused: v = sum_slices(vpart) -> CGENN norm(na) -> pair products with u -> P bf16
__global__ void pair_norm_p(const u16* __restrict__ up, const float* __restrict__ vpart,
                            const float* __restrict__ na, u16* __restrict__ Pp,
                            int PS, int M, int KS)
{
  int t = blockIdx.x * 256 + threadIdx.x;
  if (t >= PS) return;
  int m = t % M;
  float u[8], v[8];
  #pragma unroll
  for (int jj = 0; jj < 8; ++jj) {
    u[jj] = bf2f(up[(size_t)jj * PS + t]);
    float s = 0.f;
    for (int sl = 0; sl < KS; ++sl) s += vpart[(size_t)(sl * 8 + jj) * PS + t];
    v[jj] = s;
  }
  float q[4];
  q[0] = sqrtf(v[0] * v[0]);
  q[1] = sqrtf(v[1] * v[1] + v[2] * v[2] + v[3] * v[3]);
  q[2] = sqrtf(v[4] * v[4] + v[5] * v[5] + v[6] * v[6]);
  q[3] = sqrtf(v[7] * v[7]);
  float sc[4];
  #pragma unroll
  for (int gg = 0; gg < 4; ++gg) {
    float sa = sigm(na[m * 4 + gg]);
    sc[gg] = 1.0f / (sa * (q[gg] - 1.0f) + 1.0f + 1e-6f);
  }
  #pragma unroll
  for (int jj = 0; jj < 8; ++jj) v[jj] *= sc[GRADE[jj]];
  float p[44];
  #pragma unroll
  for (int c = 0; c < 44; ++c) p[c] = 0.f;
  #pragma unroll
  for (int e = 0; e < 64; ++e)
    p[PP_C[e]] += PP_S[e] * u[PP_I[e]] * v[PP_K[e]];
  #pragma unroll
  for (int c = 0; c < 44; ++c) Pp[(size_t)c * PS + t] = f2bf(p[c]);
}

// h = mv_silu((sum_slices + bias0)/sqrt2) -> bf16 planes
__global__ void bias_silu_p(const float* __restrict__ hpart, const float* __restrict__ bias,
                            const float* __restrict__ ga, const float* __restrict__ gb,
                            u16* __restrict__ sh, int PS, int M, int KS)
{
  int t = blockIdx.x * 256 + threadIdx.x;
  if (t >= PS) return;
  int m = t % M;
  float v[8];
  #pragma unroll
  for (int jj = 0; jj < 8; ++jj) {
    float s = 0.f;
    for (int sl = 0; sl < KS; ++sl) s += hpart[(size_t)(sl * 8 + jj) * PS + t];
    v[jj] = s;
  }
  v[0] += bias[m];
  #pragma unroll
  for (int jj = 0; jj < 8; ++jj) v[jj] *= RSQRT2F;
  float inv[4];
  inv[0] = v[0];
  inv[1] = v[1]*v[1] + v[2]*v[2] + v[3]*v[3];
  inv[2] = v[4]*v[4] + v[5]*v[5] + v[6]*v[6];
  inv[3] = v[7]*v[7];
  float gt[4];
  #pragma unroll
  for (int gg = 0; gg < 4; ++gg)
    gt[gg] = sigm(ga[m * 4 + gg] * inv[gg] + gb[m * 4 + gg]);
  #pragma unroll
  for (int jj = 0; jj < 8; ++jj)
    sh[(size_t)jj * PS + t] = f2bf(v[jj] * gt[GRADE[jj]]);
}

// h2 = mv_silu((llg + bias0 + cwGP(u, norm(hr); wg))/sqrt2) -> bf16 planes (in-place on sh ok)
__global__ void cw_silu_p(const float* __restrict__ llg, const u16* __restrict__ up,
                          const float* __restrict__ hrraw, const float* __restrict__ na,
                          const float* __restrict__ wg, const float* __restrict__ bias,
                          const float* __restrict__ ga, const float* __restrict__ gb,
                          u16* __restrict__ sh, int PS, int M)
{
  int t = blockIdx.x * 256 + threadIdx.x;
  if (t >= PS) return;
  int n = t % M;
  float acc[8], u[8], v[8], w[20];
  #pragma unroll
  for (int jj = 0; jj < 8; ++jj) {
    acc[jj] = llg[(size_t)jj * PS + t];
    u[jj]   = bf2f(up[(size_t)jj * PS + t]);
    v[jj]   = hrraw[(size_t)jj * PS + t];
  }
  // fused normalization of hr
  float q[4];
  q[0] = sqrtf(v[0] * v[0]);
  q[1] = sqrtf(v[1] * v[1] + v[2] * v[2] + v[3] * v[3]);
  q[2] = sqrtf(v[4] * v[4] + v[5] * v[5] + v[6] * v[6]);
  q[3] = sqrtf(v[7] * v[7]);
  float sc[4];
  #pragma unroll
  for (int gg = 0; gg < 4; ++gg) {
    float sa = sigm(na[n * 4 + gg]);
    sc[gg] = 1.0f / (sa * (q[gg] - 1.0f) + 1.0f + 1e-6f);
  }
  #pragma unroll
  for (int jj = 0; jj < 8; ++jj) v[jj] *= sc[GRADE[jj]];
  #pragma unroll
  for (int qq = 0; qq < 5; ++qq)
    *(float4*)(w + qq * 4) = *(const float4*)(wg + (size_t)n * 20 + qq * 4);
  acc[0] += bias[n];
  #pragma unroll
  for (int e = 0; e < 64; ++e)
    acc[PP_J[e]] += PP_S[e] * u[PP_I[e]] * v[PP_K[e]] * w[PP_T[e]];
  #pragma unroll
  for (int jj = 0; jj < 8; ++jj) acc[jj] *= RSQRT2F;
  float inv[4];
  inv[0] = acc[0];
  inv[1] = acc[1]*acc[1] + acc[2]*acc[2] + acc[3]*acc[3];
  inv[2] = acc[4]*acc[4] + acc[5]*acc[5] + acc[6]*acc[6];
  inv[3] = acc[7]*acc[7];
  float gt[4];
  #pragma unroll
  for (int gg = 0; gg < 4; ++gg)
    gt[gg] = sigm(ga[n * 4 + gg] * inv[gg] + gb[n * 4 + gg]);
  #pragma unroll
  for (int jj = 0; jj < 8; ++jj)
    sh[(size_t)jj * PS + t] = f2bf(acc[jj] * gt[GRADE[jj]]);
}

// out[b,m,j] = (sum_slices + bias0)/sqrt2, planar -> interleaved
__global__ void final_p(const float* __restrict__ pre, const float* __restrict__ bias,
                        float* __restrict__ outp, int PS, int M, int KS)
{
  int t = blockIdx.x * 256 + threadIdx.x;
  if (t >= PS) return;
  int m = t % M;
  float v[8];
  #pragma unroll
  for (int jj = 0; jj < 8; ++jj) {
    float s = 0.f;
    for (int sl = 0; sl < KS; ++sl) s += pre[(size_t)(sl * 8 + jj) * PS + t];
    v[jj] = s;
  }
  v[0] += bias[m];
  #pragma unroll
  for (int jj = 0; jj < 8; ++jj) v[jj] *= RSQRT2F;
  *(float4*)(outp + (size_t)t * 8)     = *(float4*)(v);
  *(float4*)(outp + (size_t)t * 8 + 4) = *(float4*)(v + 4);
}

// ============================================================================
extern "C" void kernel_launch(void* const* d_in, const int* in_sizes, int n_in,
                              void* d_out, int out_size, void* d_ws, size_t ws_size,
                              hipStream_t stream)
{
  const float* x     = (const float*)d_in[0];
  const float* lr1_w = (const float*)d_in[1];
  const float* n1_a  = (const float*)d_in[2];
  const float* ll1_w = (const float*)d_in[3];
  const float* ll1_b = (const float*)d_in[4];
  const float* w1    = (const float*)d_in[5];
  const float* act_a = (const float*)d_in[6];
  const float* act_b = (const float*)d_in[7];
  const float* lrg_w = (const float*)d_in[8];
  const float* ng_a  = (const float*)d_in[9];
  const float* llg_w = (const float*)d_in[10];
  const float* llg_b = (const float*)d_in[11];
  const float* wg    = (const float*)d_in[12];
  const float* lr2_w = (const float*)d_in[13];
  const float* n2_a  = (const float*)d_in[14];
  const float* ll2_w = (const float*)d_in[15];
  const float* ll2_b = (const float*)d_in[16];
  const float* w2    = (const float*)d_in[17];
  float* out = (float*)d_out;

  // ---- workspace carve-up ----
  u16* W = (u16*)d_ws;
  size_t o = 0;
  u16* WL1  = W + o; o +=  262144;   // [4][256*256]
  u16* WLL1 = W + o; o +=  524288;   // [4][512*256]
  u16* WG1  = W + o; o += 2621440;   // [20][512*256]
  u16* WLRG = W + o; o += 1048576;   // [4][512*512]
  u16* WLLG = W + o; o += 1048576;
  u16* WLR2 = W + o; o += 1048576;
  u16* WLL2 = W + o; o +=  262144;   // [4][128*512]
  u16* WG2  = W + o; o += 1310720;   // [20][128*512]
  u16* XB   = W + o; o += 2097152;   // [8][1024*256]
  u16* HB   = W + o; o += 4194304;   // [8][1024*512] (h1 bf16, then h2 bf16)
  u16* P    = W + o; o += 23068672;  // [44][1024*512]
  // fp32 region (total 64 MB; lifetimes disjoint per comments)
  float* f1 = (float*)(W + o);            // 8,388,608 f: preXr_part(16MB) / h1_part(32MB) / lr2_part(32MB)
  float* f2 = f1 + 8388608;               // 8,388,608 f: hr(16MB)+llg(16MB) / outPre_part(32MB)
  float* hr   = f2;
  float* llgO = f2 + 4194304;
  // total ws use: 74,973,184 + 67,108,864 = 142,082,048 B

  dim3 blk(256);
  const int PS1 = 1024 * 256, PS2 = 1024 * 512, PSO = 1024 * 128;

  // ---- repacks (every call; ws re-poisoned) ----
  RepackArgs ra = {{
    {lr1_w, WL1, 65536, 4}, {ll1_w, WLL1, 131072, 4}, {w1, WG1, 131072, 20},
    {lrg_w, WLRG, 262144, 4}, {llg_w, WLLG, 262144, 4}, {lr2_w, WLR2, 262144, 4},
    {ll2_w, WLL2, 65536, 4}, {w2, WG2, 65536, 20}}};
  repack_all<<<dim3(1024, 8), blk, 0, stream>>>(ra);
  xcast_kernel<<<PS1 / 256, blk, 0, stream>>>(x, XB, PS1);

  // ---- fcgp1 (N=256, M=512) ----
  // lr1: KS=2 -> grid z=16, partials in f1
  mfma_gemm<<<dim3(2, 8, 16), blk, 0, stream>>>(XB, nullptr, WL1, nullptr, nullptr,
      f1, nullptr, 256, 256, 0, PS1, PS1, 1, 2);
  pair_norm_p<<<PS1 / 256, blk, 0, stream>>>(XB, f1, n1_a, P, PS1, 256, 2);
  // ll1 + w1 aug GEMM: KS=2 -> grid z=16, partials in f1
  mfma_gemm<<<dim3(4, 8, 16), blk, 0, stream>>>(XB, P, WLL1, nullptr, WG1,
      f1, nullptr, 256, 512, 1, PS1, PS2, 1, 2);
  bias_silu_p<<<PS2 / 256, blk, 0, stream>>>(f1, ll1_b, act_a, act_b, HB, PS2, 512, 2);

  // ---- channel-wise GP layer (N=512, M=512): lrg + llg fused, KS=1 ----
  mfma_gemm<<<dim3(4, 8, 16), blk, 0, stream>>>(HB, nullptr, WLRG, WLLG, nullptr,
      hr, llgO, 512, 512, 0, PS2, PS2, 0, 3);
  cw_silu_p<<<PS2 / 256, blk, 0, stream>>>(llgO, HB, hr, ng_a, wg, llg_b, act_a, act_b,
      HB, PS2, 512);

  // ---- fcgp2 (N=512, M=128) ----
  mfma_gemm<<<dim3(4, 8, 16), blk, 0, stream>>>(HB, nullptr, WLR2, nullptr, nullptr,
      f1, nullptr, 512, 512, 0, PS2, PS2, 1, 3);
  pair_norm_p<<<PS2 / 256, blk, 0, stream>>>(HB, f1, n2_a, P, PS2, 512, 2);
  // ll2 + w2 aug GEMM: KS=8 -> grid z=64, partials in f2 (hr/llg dead)
  mfma_gemm<<<dim3(1, 8, 64), blk, 0, stream>>>(HB, P, WLL2, nullptr, WG2,
      f2, nullptr, 512, 128, 1, PS2, PSO, 3, 3);
  final_p<<<PSO / 256, blk, 0, stream>>>(f2, ll2_b, out, PSO, 128, 8);
}